// Round 9
// baseline (223.401 us; speedup 1.0000x reference)
//
#include <hip/hip_runtime.h>
#include <hip/hip_bf16.h>
#include <type_traits>

typedef __attribute__((ext_vector_type(8))) __bf16 bf16x8;
typedef __attribute__((ext_vector_type(2))) float f32x2;
typedef __attribute__((ext_vector_type(4))) float f32x4;
typedef __attribute__((ext_vector_type(16))) float f32x16;

#define MFMA16(a, b, c) __builtin_amdgcn_mfma_f32_16x16x32_bf16((a), (b), (c), 0, 0, 0)
#define MFMA32(a, b, c) __builtin_amdgcn_mfma_f32_32x32x16_bf16((a), (b), (c), 0, 0, 0)

template <bool B> struct BoolC { static constexpr bool value = B; };

__device__ __forceinline__ unsigned short f2bf(float f) {
    unsigned u = __builtin_bit_cast(unsigned, f);
    u = (u + 0x7fffu + ((u >> 16) & 1u)) >> 16;
    return (unsigned short)u;
}

__device__ __forceinline__ float bf2f(unsigned short u) {
    return __builtin_bit_cast(float, (unsigned)u << 16);
}

__device__ __forceinline__ unsigned cvt_pk_bf16(float lo, float hi) {
    unsigned r;
    asm("v_cvt_pk_bf16_f32 %0, %1, %2" : "=v"(r) : "v"(lo), "v"(hi));
    return r;
}

// swaps a.hi32lanes <-> b.lo32lanes
__device__ __forceinline__ void permswap(unsigned& a, unsigned& b) {
    asm("v_permlane32_swap_b32 %0, %1" : "+v"(a), "+v"(b));
}

__device__ __forceinline__ void gll16(const void* g, void* l) {
    __builtin_amdgcn_global_load_lds((const __attribute__((address_space(1))) void*)g,
                                     (__attribute__((address_space(3))) void*)l, 16, 0, 0);
}

// u in [0,24) -> (qt, base); nc = next_base - base.  (chunks of 6-7 kv tiles)
__device__ __forceinline__ void chunk_map(int u, int& qt, int& base, int& nc) {
    if (u < 1)       { qt = 0; base = 0;  nc = 1; }
    else if (u < 3)  { qt = 1; base = 1;  nc = 2; }
    else if (u < 5)  { qt = 2; base = 3;  nc = 2; }
    else if (u < 8)  { qt = 3; base = 5;  nc = 3; }
    else if (u < 11) { qt = 4; base = 8;  nc = 3; }
    else if (u < 15) { qt = 5; base = 11; nc = 4; }
    else if (u < 19) { qt = 6; base = 15; nc = 4; }
    else             { qt = 7; base = 19; nc = 5; }
}

// ---------------- fused fp32->bf16 converts + trig table (one launch) ----------------
__global__ __launch_bounds__(256) void cvt_fused(const float4* __restrict__ x,
                                                 const float4* __restrict__ wq,
                                                 const float4* __restrict__ wk,
                                                 const float4* __restrict__ wv,
                                                 const float4* __restrict__ wo,
                                                 ushort4* __restrict__ xb,
                                                 ushort4* __restrict__ wqkvb,
                                                 ushort4* __restrict__ wob,
                                                 float2* __restrict__ tbl) {
    int i = blockIdx.x * 256 + threadIdx.x;
    if (i < 2752512) {
        const float4* src; ushort4* dst; int j;
        if (i < 2097152)      { src = x;  dst = xb;             j = i; }
        else if (i < 2359296) { src = wq; dst = wqkvb;          j = i - 2097152; }
        else if (i < 2424832) { src = wk; dst = wqkvb + 262144; j = i - 2359296; }
        else if (i < 2490368) { src = wv; dst = wqkvb + 327680; j = i - 2424832; }
        else                  { src = wo; dst = wob;            j = i - 2490368; }
        float4 v = src[j];
        ushort4 o;
        o.x = f2bf(v.x); o.y = f2bf(v.y); o.z = f2bf(v.z); o.w = f2bf(v.w);
        dst[j] = o;
    } else {
        int j = i - 2752512;              // 65536 = 2048*32
        int t = j >> 5, k = j & 31;
        float inv = powf(10000.0f, -(float)(2 * k) * (1.0f / 64.0f));
        float a = (float)t * inv;
        tbl[j] = make_float2(cosf(a), sinf(a));
    }
}

// ---------------- GEMM: C(MxN) = A(MxK) @ Bt(NxK)^T, bf16 in, fp32/bf16 out ----------------
template <typename OT>
__global__ __launch_bounds__(256) void gemm_bt_t(const unsigned short* __restrict__ A,
                                                 const unsigned short* __restrict__ Bt,
                                                 OT* __restrict__ C, int M, int N, int K) {
    __shared__ unsigned short As[2][128 * 32];
    __shared__ unsigned short Bs[2][128 * 32];
    const int tid = threadIdx.x;
    const int wid = tid >> 6, lane = tid & 63;
    const size_t brow = (size_t)blockIdx.x * 128, bcol = (size_t)blockIdx.y * 128;
    const int nkt = K >> 5;

    auto stage = [&](int buf, int kt) {
#pragma unroll
        for (int j = 0; j < 2; ++j) {
            int e = (j * 256 + tid) * 8;
            int r = e >> 5, c = e & 31;
            gll16(A + (brow + r) * K + kt * 32 + c, &As[buf][e]);
        }
#pragma unroll
        for (int j = 0; j < 2; ++j) {
            int e = (j * 256 + tid) * 8;
            int r = e >> 5, c = e & 31;
            gll16(Bt + (bcol + r) * K + kt * 32 + c, &Bs[buf][e]);
        }
    };

    f32x4 acc[4][4] = {};
    const int wm = (wid >> 1) * 64, wn = (wid & 1) * 64;
    const int fr = lane & 15, fk = (lane >> 4) * 8;

    stage(0, 0);
    for (int kt = 0; kt < nkt; ++kt) {
        __syncthreads();
        if (kt + 1 < nkt) stage((kt + 1) & 1, kt + 1);
        const int buf = kt & 1;
        bf16x8 af[4], bfr[4];
#pragma unroll
        for (int i = 0; i < 4; ++i)
            af[i] = *(const bf16x8*)&As[buf][(wm + i * 16 + fr) * 32 + fk];
#pragma unroll
        for (int i = 0; i < 4; ++i)
            bfr[i] = *(const bf16x8*)&Bs[buf][(wn + i * 16 + fr) * 32 + fk];
#pragma unroll
        for (int i = 0; i < 4; ++i)
#pragma unroll
            for (int j = 0; j < 4; ++j)
                acc[i][j] = MFMA16(af[i], bfr[j], acc[i][j]);
    }

    const int orow = (lane >> 4) * 4, ocol = lane & 15;
#pragma unroll
    for (int i = 0; i < 4; ++i)
#pragma unroll
        for (int j = 0; j < 4; ++j)
#pragma unroll
            for (int r = 0; r < 4; ++r) {
                size_t idx = (brow + wm + i * 16 + orow + r) * N + (bcol + wn + j * 16 + ocol);
                if constexpr (std::is_same_v<OT, unsigned short>)
                    C[idx] = f2bf(acc[i][j][r]);
                else
                    C[idx] = acc[i][j][r];
            }
}

// ---------------- RoPE + QK-RMSNorm (bf16 qkv in); q pre-scaled by 0.125*log2e ----------------
__global__ __launch_bounds__(256) void rope_norm(const unsigned short* __restrict__ qkvb,
                                                 const float2* __restrict__ tbl,
                                                 unsigned short* __restrict__ qb,
                                                 unsigned short* __restrict__ kb) {
    int unit = blockIdx.x * 4 + (threadIdx.x >> 6);  // 8192*20 units (16 q + 4 k heads)
    int lane = threadIdx.x & 63;
    int row = unit / 20;
    int hh = unit - row * 20;
    int b = row >> 11, t = row & 2047;
    int col = (hh < 16) ? hh * 64 : 1024 + (hh - 16) * 64;
    float x = bf2f(qkvb[(size_t)row * 1536 + col + lane]);
    float partner = __shfl_xor(x, 1);
    float2 cs = tbl[t * 32 + (lane >> 1)];
    float sgn = (lane & 1) ? cs.y : -cs.y;
    float o = x * cs.x + partner * sgn;
    float ss = o * o;
#pragma unroll
    for (int off = 1; off < 64; off <<= 1) ss += __shfl_xor(ss, off);
    o = o * rsqrtf(ss * (1.0f / 64.0f) + 1e-6f);
    if (hh < 16) o *= 0.18033688f;   // 1/sqrt(64) * log2(e), folded into q
    unsigned short ob = f2bf(o);
    if (hh < 16)
        qb[(((size_t)(b * 16 + hh)) * 2048 + t) * 64 + lane] = ob;
    else
        kb[(((size_t)(b * 4 + (hh - 16))) * 2048 + t) * 64 + lane] = ob;
}

// ---------------- V transpose from qkv v-region: -> [B*KVH][D][T] ----------------
__global__ __launch_bounds__(256) void vtrans(const unsigned short* __restrict__ qkvb,
                                              unsigned short* __restrict__ vt) {
    __shared__ unsigned short tile[64][72];
    int bk = blockIdx.y, t0 = blockIdx.x * 64;
    int b = bk >> 2, kvh = bk & 3;
    int i = threadIdx.x >> 2, c0 = (threadIdx.x & 3) * 16;
    const unsigned short* src = qkvb + ((size_t)(b * 2048 + t0)) * 1536 + 1280 + kvh * 64;
#pragma unroll
    for (int j = 0; j < 16; ++j) tile[i][c0 + j] = src[(size_t)i * 1536 + c0 + j];
    __syncthreads();
    unsigned short* dst = vt + (size_t)bk * 64 * 2048 + (size_t)i * 2048 + t0 + c0;
#pragma unroll
    for (int j = 0; j < 16; ++j) dst[j] = tile[c0 + j][i];
}

// ---------------- causal flash attention ----------------
// 64 q-rows/wave (2x 32-row subtiles): shared K-frags feed both subtiles' QK, shared V-frags
// feed both PVs -> 16 ds_read serve 32 MFMA32. In-register softmax (T12), static shift
// p=exp2(s+S0) (log2e folded into q). Counted-vmcnt 3-buffer staging. kv-chunks of 6-7
// tiles (24 slots/bh, near-uniform) -> bf16 partials PLAIN-stored per slot (no atomics,
// no memset); fin sums. XCD-chunked grid (1536 = 8*192).
__global__ __launch_bounds__(256) void attn_fwd(const unsigned short* __restrict__ qb,
                                                const unsigned short* __restrict__ kbuf,
                                                const unsigned short* __restrict__ vt,
                                                unsigned short* __restrict__ Pp,
                                                float* __restrict__ Lp) {
    int orig = blockIdx.x;
    int wg = (orig & 7) * 192 + (orig >> 3);
    int bh = wg / 24;
    int u = 23 - (wg - bh * 24);          // big-qt chunks first
    int qt, base, nc;
    chunk_map(u, qt, base, nc);
    const int ci = u - base;
    const int nkt = 4 * (qt + 1);
    const int t0 = ci * nkt / nc, t1 = (ci + 1) * nkt / nc;
    const int qbase = qt << 8;

    int b = bh >> 4, h = bh & 15, kvh = h >> 2;
    int tid = threadIdx.x, wid = tid >> 6, lane = tid & 63;
    int qrow0 = qbase + wid * 64;         // wave owns 64 rows (2 subtiles of 32)
    const unsigned short* Q = qb + ((size_t)(b * 16 + h)) * 2048 * 64;
    const unsigned short* Kp = kbuf + ((size_t)(b * 4 + kvh)) * 2048 * 64;
    const unsigned short* Vp = vt + ((size_t)(b * 4 + kvh)) * 64 * 2048;
    const int q32 = lane & 31, hi = lane >> 5;
    const int swz = (q32 & 7) ^ ((q32 >> 3) & 3);

    __shared__ unsigned short Klds[3][4096];
    __shared__ unsigned short Vlds[3][4096];

    auto stage = [&](int buf, int kt) {        // 4 gll16 per thread
#pragma unroll
        for (int j = 0; j < 2; ++j) {
            int t = j * 256 + tid;
            int k = t >> 3, c = (t & 7) ^ (k & 7) ^ ((k >> 3) & 3);
            gll16(Kp + ((size_t)(kt * 64 + k)) * 64 + c * 8, &Klds[buf][t * 8]);
        }
#pragma unroll
        for (int j = 0; j < 2; ++j) {
            int t = j * 256 + tid;
            int d = t >> 3, c = (t & 7) ^ (d & 7) ^ ((d >> 3) & 3);
            gll16(Vp + (size_t)d * 2048 + kt * 64 + c * 8, &Vlds[buf][t * 8]);
        }
    };

    // Q fragments for both subtiles
    bf16x8 qf[2][4];
#pragma unroll
    for (int m = 0; m < 2; ++m)
#pragma unroll
        for (int kd = 0; kd < 4; ++kd)
            qf[m][kd] = *(const bf16x8*)&Q[(qrow0 + m * 32 + q32) * 64 + kd * 16 + hi * 8];

    f32x16 accO[2][2] = {};
    f32x2 lr2[2] = {{0.0f, 0.0f}, {0.0f, 0.0f}};
    f32x16 s0v;
#pragma unroll
    for (int i = 0; i < 16; ++i) s0v[i] = -11.54156036f;   // -8*log2(e)

    const int nt = t1 - t0;
    stage(0, t0);
    if (nt > 1) stage(1, t0 + 1);
    int cur = 0;
    for (int kt = t0; kt < t1; ++kt) {
        if (kt + 1 < t1) { asm volatile("s_waitcnt vmcnt(4)" ::: "memory"); }
        else             { asm volatile("s_waitcnt vmcnt(0)" ::: "memory"); }
        __builtin_amdgcn_sched_barrier(0);
        __builtin_amdgcn_s_barrier();
        if (kt + 2 < t1) stage(cur == 0 ? 2 : cur - 1, kt + 2);
        const int kb0 = kt * 64;
        if (kb0 <= qrow0 + 31) {           // wave-uniform; identical for both subtiles
            // joint QK: shared kf -> both subtiles
            f32x16 s[2][2] = {{s0v, s0v}, {s0v, s0v}};
            __builtin_amdgcn_s_setprio(1);
#pragma unroll
            for (int j = 0; j < 2; ++j) {
                int row = j * 32 + q32;
#pragma unroll
                for (int kd = 0; kd < 4; ++kd) {
                    bf16x8 kf = *(const bf16x8*)&Klds[cur][row * 64 + ((2 * kd + hi) ^ swz) * 8];
                    s[0][j] = MFMA32(kf, qf[0][kd], s[0][j]);
                    s[1][j] = MFMA32(kf, qf[1][kd], s[1][j]);
                }
            }
            __builtin_amdgcn_s_setprio(0);
            bf16x8 pf[2][4];
            auto build = [&](auto mc) {
                constexpr bool MASKED = decltype(mc)::value;
#pragma unroll
                for (int m = 0; m < 2; ++m) {
                    const int qg = qrow0 + m * 32 + q32;
#pragma unroll
                    for (int j = 0; j < 2; ++j) {
                        float p[16];
#pragma unroll
                        for (int r = 0; r < 16; ++r) {
                            float v = __builtin_exp2f(s[m][j][r]);
                            if (MASKED) {
                                int key = kb0 + j * 32 + (r & 3) + 8 * (r >> 2) + 4 * hi;
                                if (key > qg) v = 0.0f;
                            }
                            p[r] = v;
                        }
#pragma unroll
                        for (int i = 0; i < 8; ++i) {
                            f32x2 pp = {p[2 * i], p[2 * i + 1]};
                            asm("v_pk_add_f32 %0, %0, %1" : "+v"(lr2[m]) : "v"(pp));
                        }
#pragma unroll
                        for (int kl = 0; kl < 2; ++kl) {
                            unsigned c0 = cvt_pk_bf16(p[8 * kl + 0], p[8 * kl + 1]);
                            unsigned c1 = cvt_pk_bf16(p[8 * kl + 4], p[8 * kl + 5]);
                            unsigned c2 = cvt_pk_bf16(p[8 * kl + 2], p[8 * kl + 3]);
                            unsigned c3 = cvt_pk_bf16(p[8 * kl + 6], p[8 * kl + 7]);
                            permswap(c0, c1);
                            permswap(c2, c3);
                            union { bf16x8 v; unsigned u[4]; } pk;
                            pk.u[0] = c0; pk.u[1] = c2; pk.u[2] = c1; pk.u[3] = c3;
                            pf[m][j * 2 + kl] = pk.v;
                        }
                    }
                }
            };
            if (kb0 + 63 > qrow0) build(BoolC<true>{});
            else                  build(BoolC<false>{});
            // joint PV: shared vf -> both subtiles
            __builtin_amdgcn_s_setprio(1);
#pragma unroll
            for (int nd = 0; nd < 2; ++nd) {
                int row = nd * 32 + q32;
#pragma unroll
                for (int ks = 0; ks < 4; ++ks) {
                    bf16x8 vf = *(const bf16x8*)&Vlds[cur][row * 64 + ((2 * ks + hi) ^ swz) * 8];
                    accO[0][nd] = MFMA32(pf[0][ks], vf, accO[0][nd]);
                    accO[1][nd] = MFMA32(pf[1][ks], vf, accO[1][nd]);
                }
            }
            __builtin_amdgcn_s_setprio(0);
        }
        cur = (cur == 2) ? 0 : cur + 1;
    }

    // per-subtile denominator merge across lane halves
    float L[2];
#pragma unroll
    for (int m = 0; m < 2; ++m) {
        float lr = lr2[m][0] + lr2[m][1];
        unsigned la = __builtin_bit_cast(unsigned, lr), lb = la;
        permswap(la, lb);
        L[m] = __builtin_bit_cast(float, la) + __builtin_bit_cast(float, lb);
    }

    // plain bf16 partial stores (slot fully owned by this block; no atomics)
    const size_t slot = ((size_t)bh * 24 + u) * 256 + wid * 64;
    unsigned short* Pw = Pp + slot * 64;
#pragma unroll
    for (int m = 0; m < 2; ++m)
#pragma unroll
        for (int nd = 0; nd < 2; ++nd)
#pragma unroll
            for (int r = 0; r < 16; ++r) {
                int lrow = m * 32 + (r & 3) + 8 * (r >> 2) + 4 * hi;
                Pw[(size_t)lrow * 64 + nd * 32 + q32] = f2bf(accO[m][nd][r]);
            }
    if (lane < 32) {
        Lp[slot + q32] = L[0];
        Lp[slot + 32 + q32] = L[1];
    }
}

// ---------------- finalize: y[row] = (sum_ci O_ci) / (sum_ci L_ci) -> bf16 ----------------
__global__ __launch_bounds__(256) void attn_fin(const unsigned short* __restrict__ Pp,
                                                const float* __restrict__ Lp,
                                                unsigned short* __restrict__ y) {
    int idx = blockIdx.x * 256 + threadIdx.x;   // 2,097,152 = 64*2048*16
    int dg = idx & 15;
    int grow = idx >> 4;
    int bh = grow >> 11, t = grow & 2047;
    int b = bh >> 4, h = bh & 15;
    int qt = t >> 8, bse, nc, qtd;
    // base/nc chain (qt known): boundaries 0,1,3,5,8,11,15,19,24
    {
        int u_probe = 0;
        (void)u_probe;
        switch (qt) {
            case 0: bse = 0;  nc = 1; break;
            case 1: bse = 1;  nc = 2; break;
            case 2: bse = 3;  nc = 2; break;
            case 3: bse = 5;  nc = 3; break;
            case 4: bse = 8;  nc = 3; break;
            case 5: bse = 11; nc = 4; break;
            case 6: bse = 15; nc = 4; break;
            default: bse = 19; nc = 5; break;
        }
        (void)qtd;
    }
    float o0 = 0.f, o1 = 0.f, o2 = 0.f, o3 = 0.f, L = 0.f;
    for (int ci = 0; ci < nc; ++ci) {
        size_t slot = ((size_t)bh * 24 + bse + ci) * 256 + (t & 255);
        ushort4 pw = *(const ushort4*)&Pp[slot * 64 + dg * 4];
        o0 += bf2f(pw.x); o1 += bf2f(pw.y); o2 += bf2f(pw.z); o3 += bf2f(pw.w);
        L += Lp[slot];
    }
    float inv = 1.0f / L;
    ushort4 w;
    w.x = f2bf(o0 * inv); w.y = f2bf(o1 * inv);
    w.z = f2bf(o2 * inv); w.w = f2bf(o3 * inv);
    *(ushort4*)&y[((size_t)(b * 2048 + t)) * 1024 + h * 64 + dg * 4] = w;
}

extern "C" void kernel_launch(void* const* d_in, const int* in_sizes, int n_in,
                              void* d_out, int out_size, void* d_ws, size_t ws_size,
                              hipStream_t stream) {
    const float* x = (const float*)d_in[0];
    const float* wq = (const float*)d_in[1];
    const float* wk = (const float*)d_in[2];
    const float* wv = (const float*)d_in[3];
    const float* wo = (const float*)d_in[4];
    float* out = (float*)d_out;

    char* ws = (char*)d_ws;
    size_t off = 0;
    auto alloc = [&](size_t bytes) {
        void* p = ws + off;
        off += (bytes + 255) & ~(size_t)255;
        return p;
    };
    unsigned short* xb    = (unsigned short*)alloc(8192ull * 1024 * 2);   // dead after gemm1; reused as ybf
    unsigned short* wqkvb = (unsigned short*)alloc(1536ull * 1024 * 2);
    unsigned short* wob   = (unsigned short*)alloc(1024ull * 1024 * 2);
    char*           big   = (char*)alloc(50331648ull + 1572864ull);       // qkvb(24MB) -> Pp(48MB)+Lp(1.5MB)
    float2*         tbl   = (float2*)alloc(2048ull * 32 * 8);
    unsigned short* qb    = (unsigned short*)alloc(8192ull * 1024 * 2);
    unsigned short* kb    = (unsigned short*)alloc(4ull * 4 * 2048 * 64 * 2);
    unsigned short* vt    = (unsigned short*)alloc(4ull * 4 * 64 * 2048 * 2);

    unsigned short* qkvb  = (unsigned short*)big;        // bf16 [8192][1536], dead after vtrans
    unsigned short* Pp    = (unsigned short*)big;        // bf16 partials [64][24][256][64]
    float*          Lp    = (float*)(big + 50331648ull); // fp32 [64][24][256]
    unsigned short* ybf   = xb;

    // 1) fused converts + trig
    cvt_fused<<<11008, 256, 0, stream>>>((const float4*)x, (const float4*)wq, (const float4*)wk,
                                         (const float4*)wv, (const float4*)wo,
                                         (ushort4*)xb, (ushort4*)wqkvb, (ushort4*)wob, tbl);

    // 2) QKV GEMM -> bf16 [8192x1536]
    gemm_bt_t<unsigned short><<<dim3(64, 12), 256, 0, stream>>>(xb, wqkvb, qkvb, 8192, 1536, 1024);

    // 3) RoPE + QK-norm (q,k only)
    rope_norm<<<(8192 * 20) / 4, 256, 0, stream>>>(qkvb, tbl, qb, kb);

    // 4) V transpose from qkv v-region
    vtrans<<<dim3(32, 16), 256, 0, stream>>>(qkvb, vt);

    // 5) attention partials (no memset needed: every slot fully overwritten)
    attn_fwd<<<1536, 256, 0, stream>>>(qb, kb, vt, Pp, Lp);

    // 6) finalize (sum chunks, divide)
    attn_fin<<<8192, 256, 0, stream>>>(Pp, Lp, ybf);

    // 7) output GEMM -> fp32 d_out
    gemm_bt_t<float><<<dim3(64, 8), 256, 0, stream>>>(ybf, wob, out, 8192, 1024, 1024);
}

// Round 10
// 188.557 us; speedup vs baseline: 1.1848x; 1.1848x over previous
//
#include <hip/hip_runtime.h>
#include <hip/hip_bf16.h>
#include <type_traits>

typedef __attribute__((ext_vector_type(8))) __bf16 bf16x8;
typedef __attribute__((ext_vector_type(2))) float f32x2;
typedef __attribute__((ext_vector_type(4))) float f32x4;
typedef __attribute__((ext_vector_type(16))) float f32x16;

#define MFMA16(a, b, c) __builtin_amdgcn_mfma_f32_16x16x32_bf16((a), (b), (c), 0, 0, 0)
#define MFMA32(a, b, c) __builtin_amdgcn_mfma_f32_32x32x16_bf16((a), (b), (c), 0, 0, 0)

template <bool B> struct BoolC { static constexpr bool value = B; };

__device__ __forceinline__ unsigned short f2bf(float f) {
    unsigned u = __builtin_bit_cast(unsigned, f);
    u = (u + 0x7fffu + ((u >> 16) & 1u)) >> 16;
    return (unsigned short)u;
}

__device__ __forceinline__ float bf2f(unsigned short u) {
    return __builtin_bit_cast(float, (unsigned)u << 16);
}

__device__ __forceinline__ unsigned cvt_pk_bf16(float lo, float hi) {
    unsigned r;
    asm("v_cvt_pk_bf16_f32 %0, %1, %2" : "=v"(r) : "v"(lo), "v"(hi));
    return r;
}

// swaps a.hi32lanes <-> b.lo32lanes
__device__ __forceinline__ void permswap(unsigned& a, unsigned& b) {
    asm("v_permlane32_swap_b32 %0, %1" : "+v"(a), "+v"(b));
}

__device__ __forceinline__ void gll16(const void* g, void* l) {
    __builtin_amdgcn_global_load_lds((const __attribute__((address_space(1))) void*)g,
                                     (__attribute__((address_space(3))) void*)l, 16, 0, 0);
}

// ---------------- fused fp32->bf16 converts + trig table (one launch) ----------------
__global__ __launch_bounds__(256) void cvt_fused(const float4* __restrict__ x,
                                                 const float4* __restrict__ wq,
                                                 const float4* __restrict__ wk,
                                                 const float4* __restrict__ wv,
                                                 const float4* __restrict__ wo,
                                                 ushort4* __restrict__ xb,
                                                 ushort4* __restrict__ wqkvb,
                                                 ushort4* __restrict__ wob,
                                                 float2* __restrict__ tbl) {
    int i = blockIdx.x * 256 + threadIdx.x;
    if (i < 2752512) {
        const float4* src; ushort4* dst; int j;
        if (i < 2097152)      { src = x;  dst = xb;             j = i; }
        else if (i < 2359296) { src = wq; dst = wqkvb;          j = i - 2097152; }
        else if (i < 2424832) { src = wk; dst = wqkvb + 262144; j = i - 2359296; }
        else if (i < 2490368) { src = wv; dst = wqkvb + 327680; j = i - 2424832; }
        else                  { src = wo; dst = wob;            j = i - 2490368; }
        float4 v = src[j];
        ushort4 o;
        o.x = f2bf(v.x); o.y = f2bf(v.y); o.z = f2bf(v.z); o.w = f2bf(v.w);
        dst[j] = o;
    } else {
        int j = i - 2752512;              // 65536 = 2048*32
        int t = j >> 5, k = j & 31;
        float inv = powf(10000.0f, -(float)(2 * k) * (1.0f / 64.0f));
        float a = (float)t * inv;
        tbl[j] = make_float2(cosf(a), sinf(a));
    }
}

// ---------------- GEMM: C(MxN) = A(MxK) @ Bt(NxK)^T, bf16 in, fp32/bf16 out ----------------
template <typename OT>
__global__ __launch_bounds__(256) void gemm_bt_t(const unsigned short* __restrict__ A,
                                                 const unsigned short* __restrict__ Bt,
                                                 OT* __restrict__ C, int M, int N, int K) {
    __shared__ unsigned short As[2][128 * 32];
    __shared__ unsigned short Bs[2][128 * 32];
    const int tid = threadIdx.x;
    const int wid = tid >> 6, lane = tid & 63;
    const size_t brow = (size_t)blockIdx.x * 128, bcol = (size_t)blockIdx.y * 128;
    const int nkt = K >> 5;

    auto stage = [&](int buf, int kt) {
#pragma unroll
        for (int j = 0; j < 2; ++j) {
            int e = (j * 256 + tid) * 8;
            int r = e >> 5, c = e & 31;
            gll16(A + (brow + r) * K + kt * 32 + c, &As[buf][e]);
        }
#pragma unroll
        for (int j = 0; j < 2; ++j) {
            int e = (j * 256 + tid) * 8;
            int r = e >> 5, c = e & 31;
            gll16(Bt + (bcol + r) * K + kt * 32 + c, &Bs[buf][e]);
        }
    };

    f32x4 acc[4][4] = {};
    const int wm = (wid >> 1) * 64, wn = (wid & 1) * 64;
    const int fr = lane & 15, fk = (lane >> 4) * 8;

    stage(0, 0);
    for (int kt = 0; kt < nkt; ++kt) {
        __syncthreads();
        if (kt + 1 < nkt) stage((kt + 1) & 1, kt + 1);
        const int buf = kt & 1;
        bf16x8 af[4], bfr[4];
#pragma unroll
        for (int i = 0; i < 4; ++i)
            af[i] = *(const bf16x8*)&As[buf][(wm + i * 16 + fr) * 32 + fk];
#pragma unroll
        for (int i = 0; i < 4; ++i)
            bfr[i] = *(const bf16x8*)&Bs[buf][(wn + i * 16 + fr) * 32 + fk];
#pragma unroll
        for (int i = 0; i < 4; ++i)
#pragma unroll
            for (int j = 0; j < 4; ++j)
                acc[i][j] = MFMA16(af[i], bfr[j], acc[i][j]);
    }

    const int orow = (lane >> 4) * 4, ocol = lane & 15;
#pragma unroll
    for (int i = 0; i < 4; ++i)
#pragma unroll
        for (int j = 0; j < 4; ++j)
#pragma unroll
            for (int r = 0; r < 4; ++r) {
                size_t idx = (brow + wm + i * 16 + orow + r) * N + (bcol + wn + j * 16 + ocol);
                if constexpr (std::is_same_v<OT, unsigned short>)
                    C[idx] = f2bf(acc[i][j][r]);
                else
                    C[idx] = acc[i][j][r];
            }
}

// ---------------- RoPE + QK-RMSNorm (bf16 qkv in); q pre-scaled by 0.125*log2e ----------------
__global__ __launch_bounds__(256) void rope_norm(const unsigned short* __restrict__ qkvb,
                                                 const float2* __restrict__ tbl,
                                                 unsigned short* __restrict__ qb,
                                                 unsigned short* __restrict__ kb) {
    int unit = blockIdx.x * 4 + (threadIdx.x >> 6);  // 8192*20 units (16 q + 4 k heads)
    int lane = threadIdx.x & 63;
    int row = unit / 20;
    int hh = unit - row * 20;
    int b = row >> 11, t = row & 2047;
    int col = (hh < 16) ? hh * 64 : 1024 + (hh - 16) * 64;
    float x = bf2f(qkvb[(size_t)row * 1536 + col + lane]);
    float partner = __shfl_xor(x, 1);
    float2 cs = tbl[t * 32 + (lane >> 1)];
    float sgn = (lane & 1) ? cs.y : -cs.y;
    float o = x * cs.x + partner * sgn;
    float ss = o * o;
#pragma unroll
    for (int off = 1; off < 64; off <<= 1) ss += __shfl_xor(ss, off);
    o = o * rsqrtf(ss * (1.0f / 64.0f) + 1e-6f);
    if (hh < 16) o *= 0.18033688f;   // 1/sqrt(64) * log2(e), folded into q
    unsigned short ob = f2bf(o);
    if (hh < 16)
        qb[(((size_t)(b * 16 + hh)) * 2048 + t) * 64 + lane] = ob;
    else
        kb[(((size_t)(b * 4 + (hh - 16))) * 2048 + t) * 64 + lane] = ob;
}

// ---------------- V transpose from qkv v-region: -> [B*KVH][D][T] ----------------
__global__ __launch_bounds__(256) void vtrans(const unsigned short* __restrict__ qkvb,
                                              unsigned short* __restrict__ vt) {
    __shared__ unsigned short tile[64][72];
    int bk = blockIdx.y, t0 = blockIdx.x * 64;
    int b = bk >> 2, kvh = bk & 3;
    int i = threadIdx.x >> 2, c0 = (threadIdx.x & 3) * 16;
    const unsigned short* src = qkvb + ((size_t)(b * 2048 + t0)) * 1536 + 1280 + kvh * 64;
#pragma unroll
    for (int j = 0; j < 16; ++j) tile[i][c0 + j] = src[(size_t)i * 1536 + c0 + j];
    __syncthreads();
    unsigned short* dst = vt + (size_t)bk * 64 * 2048 + (size_t)i * 2048 + t0 + c0;
#pragma unroll
    for (int j = 0; j < 16; ++j) dst[j] = tile[c0 + j][i];
}

// ---------------- causal flash attention (R8 structure + plain-store combine) ----------------
// 32 q-rows/wave (VGPR ~80, ~25% occupancy). 32x32 MFMA, in-register softmax (T12),
// static shift p=exp2(s+S0) (log2e folded into q). Counted-vmcnt 3-buffer staging.
// kv-split chunks (40 slots/bh): partial bf16 O + fp32 L PLAIN-stored per slot (no atomics,
// no memset; every wave contributes in every chunk since t0 <= nkt - nkt/nc <= 2*qt).
// XCD-chunked grid (2560 = 8*320).
__global__ __launch_bounds__(256) void attn_fwd(const unsigned short* __restrict__ qb,
                                                const unsigned short* __restrict__ kbuf,
                                                const unsigned short* __restrict__ vt,
                                                unsigned short* __restrict__ Pp,
                                                float* __restrict__ Lp) {
    int orig = blockIdx.x;
    int wg = (orig & 7) * 320 + (orig >> 3);
    int bh = wg / 40;
    int u = 39 - (wg - bh * 40);          // heavy-first (large qt first)
    int qt, ci, nc;
    if (u < 4)       { qt = u;               ci = 0;            nc = 1; }
    else if (u < 12) { qt = 4 + ((u - 4) >> 1);  ci = (u - 4) & 1;  nc = 2; }
    else if (u < 24) { qt = 8 + (u - 12) / 3;    ci = (u - 12) % 3; nc = 3; }
    else             { qt = 12 + ((u - 24) >> 2); ci = (u - 24) & 3; nc = 4; }
    const int nkt = 2 * qt + 2;
    const int t0 = ci * nkt / nc, t1 = (ci + 1) * nkt / nc;
    const int qbase = qt * 128;

    int b = bh >> 4, h = bh & 15, kvh = h >> 2;
    int tid = threadIdx.x, wid = tid >> 6, lane = tid & 63;
    int qrow0 = qbase + wid * 32;
    const unsigned short* Q = qb + ((size_t)(b * 16 + h)) * 2048 * 64;
    const unsigned short* Kp = kbuf + ((size_t)(b * 4 + kvh)) * 2048 * 64;
    const unsigned short* Vp = vt + ((size_t)(b * 4 + kvh)) * 64 * 2048;
    const int q32 = lane & 31, hi = lane >> 5;
    const int swz = (q32 & 7) ^ ((q32 >> 3) & 3);

    __shared__ unsigned short Klds[3][4096];
    __shared__ unsigned short Vlds[3][4096];

    auto stage = [&](int buf, int kt) {        // 4 gll16 per thread
#pragma unroll
        for (int j = 0; j < 2; ++j) {
            int t = j * 256 + tid;
            int k = t >> 3, c = (t & 7) ^ (k & 7) ^ ((k >> 3) & 3);
            gll16(Kp + ((size_t)(kt * 64 + k)) * 64 + c * 8, &Klds[buf][t * 8]);
        }
#pragma unroll
        for (int j = 0; j < 2; ++j) {
            int t = j * 256 + tid;
            int d = t >> 3, c = (t & 7) ^ (d & 7) ^ ((d >> 3) & 3);
            gll16(Vp + (size_t)d * 2048 + kt * 64 + c * 8, &Vlds[buf][t * 8]);
        }
    };

    // Q fragments (B-operand): lane holds Q[qrow0+q32][kd*16 + hi*8 .. +7]
    bf16x8 qf[4];
#pragma unroll
    for (int kd = 0; kd < 4; ++kd)
        qf[kd] = *(const bf16x8*)&Q[(qrow0 + q32) * 64 + kd * 16 + hi * 8];

    f32x16 accO[2] = {};
    f32x2 lr2 = {0.0f, 0.0f};
    f32x16 s0v;                            // accumulator init = -8*log2(e)
#pragma unroll
    for (int i = 0; i < 16; ++i) s0v[i] = -11.54156036f;

    const int nt = t1 - t0;
    stage(0, t0);
    if (nt > 1) stage(1, t0 + 1);
    int cur = 0;
    for (int kt = t0; kt < t1; ++kt) {
        if (kt + 1 < t1) { asm volatile("s_waitcnt vmcnt(4)" ::: "memory"); }
        else             { asm volatile("s_waitcnt vmcnt(0)" ::: "memory"); }
        __builtin_amdgcn_sched_barrier(0);
        __builtin_amdgcn_s_barrier();      // raw barrier: no implicit vmcnt(0) drain
        if (kt + 2 < t1) stage(cur == 0 ? 2 : cur - 1, kt + 2);   // (cur+2)%3
        const int kb0 = kt * 64;
        if (kb0 <= qrow0 + 31) {           // wave-uniform causal skip
            // S^T = K @ Q^T: two 32-key tiles, 4 d-slices each; acc starts at S0
            f32x16 s[2] = {s0v, s0v};
            __builtin_amdgcn_s_setprio(1);
#pragma unroll
            for (int j = 0; j < 2; ++j) {
                int row = j * 32 + q32;
#pragma unroll
                for (int kd = 0; kd < 4; ++kd) {
                    bf16x8 kf = *(const bf16x8*)&Klds[cur][row * 64 + ((2 * kd + hi) ^ swz) * 8];
                    s[j] = MFMA32(kf, qf[kd], s[j]);
                }
            }
            __builtin_amdgcn_s_setprio(0);
            const int qg = qrow0 + q32;
            bf16x8 pf[4];                  // P fragment, key-slices of 16
            auto build = [&](auto mc) {
                constexpr bool MASKED = decltype(mc)::value;
#pragma unroll
                for (int j = 0; j < 2; ++j) {
                    float p[16];
#pragma unroll
                    for (int r = 0; r < 16; ++r) {
                        float v = __builtin_exp2f(s[j][r]);
                        if (MASKED) {
                            int key = kb0 + j * 32 + (r & 3) + 8 * (r >> 2) + 4 * hi;
                            if (key > qg) v = 0.0f;
                        }
                        p[r] = v;
                    }
#pragma unroll
                    for (int i = 0; i < 8; ++i) {
                        f32x2 pp = {p[2 * i], p[2 * i + 1]};
                        asm("v_pk_add_f32 %0, %0, %1" : "+v"(lr2) : "v"(pp));
                    }
#pragma unroll
                    for (int kl = 0; kl < 2; ++kl) {
                        unsigned c0 = cvt_pk_bf16(p[8 * kl + 0], p[8 * kl + 1]);
                        unsigned c1 = cvt_pk_bf16(p[8 * kl + 4], p[8 * kl + 5]);
                        unsigned c2 = cvt_pk_bf16(p[8 * kl + 2], p[8 * kl + 3]);
                        unsigned c3 = cvt_pk_bf16(p[8 * kl + 6], p[8 * kl + 7]);
                        permswap(c0, c1);  // c0 = word0, c1 = word2
                        permswap(c2, c3);  // c2 = word1, c3 = word3
                        union { bf16x8 v; unsigned u[4]; } pk;
                        pk.u[0] = c0; pk.u[1] = c2; pk.u[2] = c1; pk.u[3] = c3;
                        pf[j * 2 + kl] = pk.v;
                    }
                }
            };
            if (kb0 + 63 > qrow0) build(BoolC<true>{});   // diagonal tile: apply mask
            else                  build(BoolC<false>{});  // interior: no mask ops
            // O += P @ V : V^T rows (d) contiguous over keys in Vlds
            __builtin_amdgcn_s_setprio(1);
#pragma unroll
            for (int nd = 0; nd < 2; ++nd) {
                int row = nd * 32 + q32;
#pragma unroll
                for (int ks = 0; ks < 4; ++ks) {
                    bf16x8 vf = *(const bf16x8*)&Vlds[cur][row * 64 + ((2 * ks + hi) ^ swz) * 8];
                    accO[nd] = MFMA32(pf[ks], vf, accO[nd]);
                }
            }
            __builtin_amdgcn_s_setprio(0);
        }
        cur = (cur == 2) ? 0 : cur + 1;
    }

    // cross-half denominator merge: lane halves hold disjoint key subsets for same q
    float lrun = lr2[0] + lr2[1];
    unsigned lu = __builtin_bit_cast(unsigned, lrun);
    unsigned la = lu, lb = lu;
    permswap(la, lb);
    float L = __builtin_bit_cast(float, la) + __builtin_bit_cast(float, lb);

    // plain bf16 partial stores (slot fully owned by this block; no atomics, no memset)
    unsigned short* Pw = Pp + (((size_t)bh * 40 + u) * 128 + wid * 32) * 64;
#pragma unroll
    for (int nd = 0; nd < 2; ++nd)
#pragma unroll
        for (int r = 0; r < 16; ++r) {
            int lrow = (r & 3) + 8 * (r >> 2) + 4 * hi;
            Pw[(size_t)lrow * 64 + nd * 32 + q32] = f2bf(accO[nd][r]);
        }
    if (lane < 32)
        Lp[((size_t)bh * 40 + u) * 128 + wid * 32 + q32] = L;
}

// ---------------- finalize: y[row] = (sum_ci O_ci) / (sum_ci L_ci) -> bf16 ----------------
__global__ __launch_bounds__(256) void attn_fin(const unsigned short* __restrict__ Pp,
                                                const float* __restrict__ Lp,
                                                unsigned short* __restrict__ y) {
    int idx = blockIdx.x * 256 + threadIdx.x;   // 2,097,152 = 64*2048*16
    int dg = idx & 15;
    int grow = idx >> 4;
    int bh = grow >> 11, t = grow & 2047;
    int b = bh >> 4, h = bh & 15;
    int qt = t >> 7;
    int bse, nc;
    if (qt < 4)       { bse = qt;                nc = 1; }
    else if (qt < 8)  { bse = 4 + 2 * (qt - 4);  nc = 2; }
    else if (qt < 12) { bse = 12 + 3 * (qt - 8); nc = 3; }
    else              { bse = 24 + 4 * (qt - 12); nc = 4; }
    float o0 = 0.f, o1 = 0.f, o2 = 0.f, o3 = 0.f, L = 0.f;
    for (int ci = 0; ci < nc; ++ci) {
        size_t slot = ((size_t)bh * 40 + bse + ci) * 128 + (t & 127);
        ushort4 pw = *(const ushort4*)&Pp[slot * 64 + dg * 4];
        o0 += bf2f(pw.x); o1 += bf2f(pw.y); o2 += bf2f(pw.z); o3 += bf2f(pw.w);
        L += Lp[slot];
    }
    float inv = 1.0f / L;
    ushort4 w;
    w.x = f2bf(o0 * inv); w.y = f2bf(o1 * inv);
    w.z = f2bf(o2 * inv); w.w = f2bf(o3 * inv);
    *(ushort4*)&y[((size_t)(b * 2048 + t)) * 1024 + h * 64 + dg * 4] = w;
}

extern "C" void kernel_launch(void* const* d_in, const int* in_sizes, int n_in,
                              void* d_out, int out_size, void* d_ws, size_t ws_size,
                              hipStream_t stream) {
    const float* x = (const float*)d_in[0];
    const float* wq = (const float*)d_in[1];
    const float* wk = (const float*)d_in[2];
    const float* wv = (const float*)d_in[3];
    const float* wo = (const float*)d_in[4];
    float* out = (float*)d_out;

    char* ws = (char*)d_ws;
    size_t off = 0;
    auto alloc = [&](size_t bytes) {
        void* p = ws + off;
        off += (bytes + 255) & ~(size_t)255;
        return p;
    };
    unsigned short* xb    = (unsigned short*)alloc(8192ull * 1024 * 2);   // dead after gemm1; reused as ybf
    unsigned short* wqkvb = (unsigned short*)alloc(1536ull * 1024 * 2);
    unsigned short* wob   = (unsigned short*)alloc(1024ull * 1024 * 2);
    char*           big   = (char*)alloc(41943040ull + 1310720ull);       // qkvb(24MB) -> Pp(40MB)+Lp(1.25MB)
    float2*         tbl   = (float2*)alloc(2048ull * 32 * 8);
    unsigned short* qb    = (unsigned short*)alloc(8192ull * 1024 * 2);
    unsigned short* kb    = (unsigned short*)alloc(4ull * 4 * 2048 * 64 * 2);
    unsigned short* vt    = (unsigned short*)alloc(4ull * 4 * 64 * 2048 * 2);

    unsigned short* qkvb  = (unsigned short*)big;        // bf16 [8192][1536], dead after vtrans
    unsigned short* Pp    = (unsigned short*)big;        // bf16 partials [64][40][128][64]
    float*          Lp    = (float*)(big + 41943040ull); // fp32 [64][40][128]
    unsigned short* ybf   = xb;

    // 1) fused converts + trig
    cvt_fused<<<11008, 256, 0, stream>>>((const float4*)x, (const float4*)wq, (const float4*)wk,
                                         (const float4*)wv, (const float4*)wo,
                                         (ushort4*)xb, (ushort4*)wqkvb, (ushort4*)wob, tbl);

    // 2) QKV GEMM -> bf16 [8192x1536]
    gemm_bt_t<unsigned short><<<dim3(64, 12), 256, 0, stream>>>(xb, wqkvb, qkvb, 8192, 1536, 1024);

    // 3) RoPE + QK-norm (q,k only)
    rope_norm<<<(8192 * 20) / 4, 256, 0, stream>>>(qkvb, tbl, qb, kb);

    // 4) V transpose from qkv v-region
    vtrans<<<dim3(32, 16), 256, 0, stream>>>(qkvb, vt);

    // 5) attention partials (plain stores; every slot fully overwritten)
    attn_fwd<<<2560, 256, 0, stream>>>(qb, kb, vt, Pp, Lp);

    // 6) finalize (sum chunks, divide)
    attn_fin<<<8192, 256, 0, stream>>>(Pp, Lp, ybf);

    // 7) output GEMM -> fp32 d_out
    gemm_bt_t<float><<<dim3(64, 8), 256, 0, stream>>>(ybf, wob, out, 8192, 1024, 1024);
}

// Round 11
// 174.827 us; speedup vs baseline: 1.2778x; 1.0785x over previous
//
#include <hip/hip_runtime.h>
#include <hip/hip_bf16.h>
#include <type_traits>

typedef __attribute__((ext_vector_type(8))) __bf16 bf16x8;
typedef __attribute__((ext_vector_type(2))) float f32x2;
typedef __attribute__((ext_vector_type(4))) float f32x4;
typedef __attribute__((ext_vector_type(16))) float f32x16;

#define MFMA16(a, b, c) __builtin_amdgcn_mfma_f32_16x16x32_bf16((a), (b), (c), 0, 0, 0)
#define MFMA32(a, b, c) __builtin_amdgcn_mfma_f32_32x32x16_bf16((a), (b), (c), 0, 0, 0)

__device__ __forceinline__ unsigned short f2bf(float f) {
    unsigned u = __builtin_bit_cast(unsigned, f);
    u = (u + 0x7fffu + ((u >> 16) & 1u)) >> 16;
    return (unsigned short)u;
}

__device__ __forceinline__ float bf2f(unsigned short u) {
    return __builtin_bit_cast(float, (unsigned)u << 16);
}

__device__ __forceinline__ unsigned cvt_pk_bf16(float lo, float hi) {
    unsigned r;
    asm("v_cvt_pk_bf16_f32 %0, %1, %2" : "=v"(r) : "v"(lo), "v"(hi));
    return r;
}

// swaps a.hi32lanes <-> b.lo32lanes
__device__ __forceinline__ void permswap(unsigned& a, unsigned& b) {
    asm("v_permlane32_swap_b32 %0, %1" : "+v"(a), "+v"(b));
}

__device__ __forceinline__ void gll16(const void* g, void* l) {
    __builtin_amdgcn_global_load_lds((const __attribute__((address_space(1))) void*)g,
                                     (__attribute__((address_space(3))) void*)l, 16, 0, 0);
}

// ---------------- fused fp32->bf16 converts + trig table (one launch) ----------------
__global__ __launch_bounds__(256) void cvt_fused(const float4* __restrict__ x,
                                                 const float4* __restrict__ wq,
                                                 const float4* __restrict__ wk,
                                                 const float4* __restrict__ wv,
                                                 const float4* __restrict__ wo,
                                                 ushort4* __restrict__ xb,
                                                 ushort4* __restrict__ wqkvb,
                                                 ushort4* __restrict__ wob,
                                                 float2* __restrict__ tbl) {
    int i = blockIdx.x * 256 + threadIdx.x;
    if (i < 2752512) {
        const float4* src; ushort4* dst; int j;
        if (i < 2097152)      { src = x;  dst = xb;             j = i; }
        else if (i < 2359296) { src = wq; dst = wqkvb;          j = i - 2097152; }
        else if (i < 2424832) { src = wk; dst = wqkvb + 262144; j = i - 2359296; }
        else if (i < 2490368) { src = wv; dst = wqkvb + 327680; j = i - 2424832; }
        else                  { src = wo; dst = wob;            j = i - 2490368; }
        float4 v = src[j];
        ushort4 o;
        o.x = f2bf(v.x); o.y = f2bf(v.y); o.z = f2bf(v.z); o.w = f2bf(v.w);
        dst[j] = o;
    } else {
        int j = i - 2752512;              // 65536 = 2048*32
        int t = j >> 5, k = j & 31;
        float inv = powf(10000.0f, -(float)(2 * k) * (1.0f / 64.0f));
        float a = (float)t * inv;
        tbl[j] = make_float2(cosf(a), sinf(a));
    }
}

// ---------------- GEMM: C(MxN) = A(MxK) @ Bt(NxK)^T, bf16 in, fp32/bf16 out ----------------
template <typename OT>
__global__ __launch_bounds__(256) void gemm_bt_t(const unsigned short* __restrict__ A,
                                                 const unsigned short* __restrict__ Bt,
                                                 OT* __restrict__ C, int M, int N, int K) {
    __shared__ unsigned short As[2][128 * 32];
    __shared__ unsigned short Bs[2][128 * 32];
    const int tid = threadIdx.x;
    const int wid = tid >> 6, lane = tid & 63;
    const size_t brow = (size_t)blockIdx.x * 128, bcol = (size_t)blockIdx.y * 128;
    const int nkt = K >> 5;

    auto stage = [&](int buf, int kt) {
#pragma unroll
        for (int j = 0; j < 2; ++j) {
            int e = (j * 256 + tid) * 8;
            int r = e >> 5, c = e & 31;
            gll16(A + (brow + r) * K + kt * 32 + c, &As[buf][e]);
        }
#pragma unroll
        for (int j = 0; j < 2; ++j) {
            int e = (j * 256 + tid) * 8;
            int r = e >> 5, c = e & 31;
            gll16(Bt + (bcol + r) * K + kt * 32 + c, &Bs[buf][e]);
        }
    };

    f32x4 acc[4][4] = {};
    const int wm = (wid >> 1) * 64, wn = (wid & 1) * 64;
    const int fr = lane & 15, fk = (lane >> 4) * 8;

    stage(0, 0);
    for (int kt = 0; kt < nkt; ++kt) {
        __syncthreads();
        if (kt + 1 < nkt) stage((kt + 1) & 1, kt + 1);
        const int buf = kt & 1;
        bf16x8 af[4], bfr[4];
#pragma unroll
        for (int i = 0; i < 4; ++i)
            af[i] = *(const bf16x8*)&As[buf][(wm + i * 16 + fr) * 32 + fk];
#pragma unroll
        for (int i = 0; i < 4; ++i)
            bfr[i] = *(const bf16x8*)&Bs[buf][(wn + i * 16 + fr) * 32 + fk];
#pragma unroll
        for (int i = 0; i < 4; ++i)
#pragma unroll
            for (int j = 0; j < 4; ++j)
                acc[i][j] = MFMA16(af[i], bfr[j], acc[i][j]);
    }

    const int orow = (lane >> 4) * 4, ocol = lane & 15;
#pragma unroll
    for (int i = 0; i < 4; ++i)
#pragma unroll
        for (int j = 0; j < 4; ++j)
#pragma unroll
            for (int r = 0; r < 4; ++r) {
                size_t idx = (brow + wm + i * 16 + orow + r) * N + (bcol + wn + j * 16 + ocol);
                if constexpr (std::is_same_v<OT, unsigned short>)
                    C[idx] = f2bf(acc[i][j][r]);
                else
                    C[idx] = acc[i][j][r];
            }
}

// ---------------- RoPE + QK-RMSNorm (bf16 qkv in); q pre-scaled by 0.125*log2e ----------------
__global__ __launch_bounds__(256) void rope_norm(const unsigned short* __restrict__ qkvb,
                                                 const float2* __restrict__ tbl,
                                                 unsigned short* __restrict__ qb,
                                                 unsigned short* __restrict__ kb) {
    int unit = blockIdx.x * 4 + (threadIdx.x >> 6);  // 8192*20 units (16 q + 4 k heads)
    int lane = threadIdx.x & 63;
    int row = unit / 20;
    int hh = unit - row * 20;
    int b = row >> 11, t = row & 2047;
    int col = (hh < 16) ? hh * 64 : 1024 + (hh - 16) * 64;
    float x = bf2f(qkvb[(size_t)row * 1536 + col + lane]);
    float partner = __shfl_xor(x, 1);
    float2 cs = tbl[t * 32 + (lane >> 1)];
    float sgn = (lane & 1) ? cs.y : -cs.y;
    float o = x * cs.x + partner * sgn;
    float ss = o * o;
#pragma unroll
    for (int off = 1; off < 64; off <<= 1) ss += __shfl_xor(ss, off);
    o = o * rsqrtf(ss * (1.0f / 64.0f) + 1e-6f);
    if (hh < 16) o *= 0.18033688f;   // 1/sqrt(64) * log2(e), folded into q
    unsigned short ob = f2bf(o);
    if (hh < 16)
        qb[(((size_t)(b * 16 + hh)) * 2048 + t) * 64 + lane] = ob;
    else
        kb[(((size_t)(b * 4 + (hh - 16))) * 2048 + t) * 64 + lane] = ob;
}

// ---------------- V transpose from qkv v-region: -> [B*KVH][D][T] ----------------
__global__ __launch_bounds__(256) void vtrans(const unsigned short* __restrict__ qkvb,
                                              unsigned short* __restrict__ vt) {
    __shared__ unsigned short tile[64][72];
    int bk = blockIdx.y, t0 = blockIdx.x * 64;
    int b = bk >> 2, kvh = bk & 3;
    int i = threadIdx.x >> 2, c0 = (threadIdx.x & 3) * 16;
    const unsigned short* src = qkvb + ((size_t)(b * 2048 + t0)) * 1536 + 1280 + kvh * 64;
#pragma unroll
    for (int j = 0; j < 16; ++j) tile[i][c0 + j] = src[(size_t)i * 1536 + c0 + j];
    __syncthreads();
    unsigned short* dst = vt + (size_t)bk * 64 * 2048 + (size_t)i * 2048 + t0 + c0;
#pragma unroll
    for (int j = 0; j < 16; ++j) dst[j] = tile[c0 + j][i];
}

// ---------------- causal flash attention ----------------
// 32 q-rows/wave, 32x32 MFMA, in-register softmax (T12), static shift p=exp2(s+S0).
// __launch_bounds__(256,4): force <=128 total regs/wave -> 4 waves/SIMD (R10 post-mortem:
// ~144 unified VGPR+AGPR capped occupancy at 2 waves/SIMD). Peak liveness halved by
// processing the two 32-key j-tiles SEQUENTIALLY (s reused). 2-buffer LDS (32KB) +
// __syncthreads pipeline (3-buf counted-vmcnt was null in R8). Plain-store partial
// combine (no atomics/memset). XCD-chunked grid (2560 = 8*320).
__global__ __launch_bounds__(256, 4) void attn_fwd(const unsigned short* __restrict__ qb,
                                                   const unsigned short* __restrict__ kbuf,
                                                   const unsigned short* __restrict__ vt,
                                                   unsigned short* __restrict__ Pp,
                                                   float* __restrict__ Lp) {
    int orig = blockIdx.x;
    int wg = (orig & 7) * 320 + (orig >> 3);
    int bh = wg / 40;
    int u = 39 - (wg - bh * 40);          // heavy-first (large qt first)
    int qt, ci, nc;
    if (u < 4)       { qt = u;               ci = 0;            nc = 1; }
    else if (u < 12) { qt = 4 + ((u - 4) >> 1);  ci = (u - 4) & 1;  nc = 2; }
    else if (u < 24) { qt = 8 + (u - 12) / 3;    ci = (u - 12) % 3; nc = 3; }
    else             { qt = 12 + ((u - 24) >> 2); ci = (u - 24) & 3; nc = 4; }
    const int nkt = 2 * qt + 2;
    const int t0 = ci * nkt / nc, t1 = (ci + 1) * nkt / nc;
    const int qbase = qt * 128;

    int b = bh >> 4, h = bh & 15, kvh = h >> 2;
    int tid = threadIdx.x, wid = tid >> 6, lane = tid & 63;
    int qrow0 = qbase + wid * 32;
    const unsigned short* Q = qb + ((size_t)(b * 16 + h)) * 2048 * 64;
    const unsigned short* Kp = kbuf + ((size_t)(b * 4 + kvh)) * 2048 * 64;
    const unsigned short* Vp = vt + ((size_t)(b * 4 + kvh)) * 64 * 2048;
    const int q32 = lane & 31, hi = lane >> 5;
    const int swz = (q32 & 7) ^ ((q32 >> 3) & 3);

    __shared__ unsigned short Klds[2][4096];
    __shared__ unsigned short Vlds[2][4096];

    auto stage = [&](int buf, int kt) {        // 4 gll16 per thread
#pragma unroll
        for (int j = 0; j < 2; ++j) {
            int t = j * 256 + tid;
            int k = t >> 3, c = (t & 7) ^ (k & 7) ^ ((k >> 3) & 3);
            gll16(Kp + ((size_t)(kt * 64 + k)) * 64 + c * 8, &Klds[buf][t * 8]);
        }
#pragma unroll
        for (int j = 0; j < 2; ++j) {
            int t = j * 256 + tid;
            int d = t >> 3, c = (t & 7) ^ (d & 7) ^ ((d >> 3) & 3);
            gll16(Vp + (size_t)d * 2048 + kt * 64 + c * 8, &Vlds[buf][t * 8]);
        }
    };

    // Q fragments (B-operand): lane holds Q[qrow0+q32][kd*16 + hi*8 .. +7]
    bf16x8 qf[4];
#pragma unroll
    for (int kd = 0; kd < 4; ++kd)
        qf[kd] = *(const bf16x8*)&Q[(qrow0 + q32) * 64 + kd * 16 + hi * 8];

    f32x16 accO[2] = {};
    f32x2 lr2 = {0.0f, 0.0f};
    f32x16 s0v;                            // accumulator init = -8*log2(e)
#pragma unroll
    for (int i = 0; i < 16; ++i) s0v[i] = -11.54156036f;

    stage(0, t0);
    for (int kt = t0; kt < t1; ++kt) {
        __syncthreads();                   // drains stage(kt); guards buffer reuse
        if (kt + 1 < t1) stage((kt + 1 - t0) & 1, kt + 1);
        const int cur = (kt - t0) & 1;
        const int kb0 = kt * 64;
        if (kb0 <= qrow0 + 31) {           // wave-uniform causal skip
            const int qg = qrow0 + q32;
            const bool diag = (kb0 + 63 > qrow0);   // wave-uniform
            bf16x8 pf[4];
            // sequential j-tiles: s registers reused across j (peak liveness halved)
#pragma unroll
            for (int j = 0; j < 2; ++j) {
                f32x16 s = s0v;
                const int row = j * 32 + q32;
                __builtin_amdgcn_s_setprio(1);
#pragma unroll
                for (int kd = 0; kd < 4; ++kd) {
                    bf16x8 kf = *(const bf16x8*)&Klds[cur][row * 64 + ((2 * kd + hi) ^ swz) * 8];
                    s = MFMA32(kf, qf[kd], s);
                }
                __builtin_amdgcn_s_setprio(0);
                float p[16];
                if (diag) {
#pragma unroll
                    for (int r = 0; r < 16; ++r) {
                        float v = __builtin_exp2f(s[r]);
                        int key = kb0 + j * 32 + (r & 3) + 8 * (r >> 2) + 4 * hi;
                        if (key > qg) v = 0.0f;
                        p[r] = v;
                    }
                } else {
#pragma unroll
                    for (int r = 0; r < 16; ++r) p[r] = __builtin_exp2f(s[r]);
                }
#pragma unroll
                for (int i = 0; i < 8; ++i) {
                    f32x2 pp = {p[2 * i], p[2 * i + 1]};
                    asm("v_pk_add_f32 %0, %0, %1" : "+v"(lr2) : "v"(pp));
                }
#pragma unroll
                for (int kl = 0; kl < 2; ++kl) {
                    unsigned c0 = cvt_pk_bf16(p[8 * kl + 0], p[8 * kl + 1]);
                    unsigned c1 = cvt_pk_bf16(p[8 * kl + 4], p[8 * kl + 5]);
                    unsigned c2 = cvt_pk_bf16(p[8 * kl + 2], p[8 * kl + 3]);
                    unsigned c3 = cvt_pk_bf16(p[8 * kl + 6], p[8 * kl + 7]);
                    permswap(c0, c1);      // c0 = word0, c1 = word2
                    permswap(c2, c3);      // c2 = word1, c3 = word3
                    union { bf16x8 v; unsigned u[4]; } pk;
                    pk.u[0] = c0; pk.u[1] = c2; pk.u[2] = c1; pk.u[3] = c3;
                    pf[j * 2 + kl] = pk.v;
                }
            }
            // O += P @ V : V^T rows (d) contiguous over keys in Vlds
            __builtin_amdgcn_s_setprio(1);
#pragma unroll
            for (int nd = 0; nd < 2; ++nd) {
                int row = nd * 32 + q32;
#pragma unroll
                for (int ks = 0; ks < 4; ++ks) {
                    bf16x8 vf = *(const bf16x8*)&Vlds[cur][row * 64 + ((2 * ks + hi) ^ swz) * 8];
                    accO[nd] = MFMA32(pf[ks], vf, accO[nd]);
                }
            }
            __builtin_amdgcn_s_setprio(0);
        }
    }

    // cross-half denominator merge: lane halves hold disjoint key subsets for same q
    float lrun = lr2[0] + lr2[1];
    unsigned lu = __builtin_bit_cast(unsigned, lrun);
    unsigned la = lu, lb = lu;
    permswap(la, lb);
    float L = __builtin_bit_cast(float, la) + __builtin_bit_cast(float, lb);

    // plain bf16 partial stores (slot fully owned by this block; no atomics, no memset)
    unsigned short* Pw = Pp + (((size_t)bh * 40 + u) * 128 + wid * 32) * 64;
#pragma unroll
    for (int nd = 0; nd < 2; ++nd)
#pragma unroll
        for (int r = 0; r < 16; ++r) {
            int lrow = (r & 3) + 8 * (r >> 2) + 4 * hi;
            Pw[(size_t)lrow * 64 + nd * 32 + q32] = f2bf(accO[nd][r]);
        }
    if (lane < 32)
        Lp[((size_t)bh * 40 + u) * 128 + wid * 32 + q32] = L;
}

// ---------------- finalize: y[row] = (sum_ci O_ci) / (sum_ci L_ci) -> bf16 ----------------
__global__ __launch_bounds__(256) void attn_fin(const unsigned short* __restrict__ Pp,
                                                const float* __restrict__ Lp,
                                                unsigned short* __restrict__ y) {
    int idx = blockIdx.x * 256 + threadIdx.x;   // 2,097,152 = 64*2048*16
    int dg = idx & 15;
    int grow = idx >> 4;
    int bh = grow >> 11, t = grow & 2047;
    int b = bh >> 4, h = bh & 15;
    int qt = t >> 7;
    int bse, nc;
    if (qt < 4)       { bse = qt;                nc = 1; }
    else if (qt < 8)  { bse = 4 + 2 * (qt - 4);  nc = 2; }
    else if (qt < 12) { bse = 12 + 3 * (qt - 8); nc = 3; }
    else              { bse = 24 + 4 * (qt - 12); nc = 4; }
    float o0 = 0.f, o1 = 0.f, o2 = 0.f, o3 = 0.f, L = 0.f;
    for (int ci = 0; ci < nc; ++ci) {
        size_t slot = ((size_t)bh * 40 + bse + ci) * 128 + (t & 127);
        ushort4 pw = *(const ushort4*)&Pp[slot * 64 + dg * 4];
        o0 += bf2f(pw.x); o1 += bf2f(pw.y); o2 += bf2f(pw.z); o3 += bf2f(pw.w);
        L += Lp[slot];
    }
    float inv = 1.0f / L;
    ushort4 w;
    w.x = f2bf(o0 * inv); w.y = f2bf(o1 * inv);
    w.z = f2bf(o2 * inv); w.w = f2bf(o3 * inv);
    *(ushort4*)&y[((size_t)(b * 2048 + t)) * 1024 + h * 64 + dg * 4] = w;
}

extern "C" void kernel_launch(void* const* d_in, const int* in_sizes, int n_in,
                              void* d_out, int out_size, void* d_ws, size_t ws_size,
                              hipStream_t stream) {
    const float* x = (const float*)d_in[0];
    const float* wq = (const float*)d_in[1];
    const float* wk = (const float*)d_in[2];
    const float* wv = (const float*)d_in[3];
    const float* wo = (const float*)d_in[4];
    float* out = (float*)d_out;

    char* ws = (char*)d_ws;
    size_t off = 0;
    auto alloc = [&](size_t bytes) {
        void* p = ws + off;
        off += (bytes + 255) & ~(size_t)255;
        return p;
    };
    unsigned short* xb    = (unsigned short*)alloc(8192ull * 1024 * 2);   // dead after gemm1; reused as ybf
    unsigned short* wqkvb = (unsigned short*)alloc(1536ull * 1024 * 2);
    unsigned short* wob   = (unsigned short*)alloc(1024ull * 1024 * 2);
    char*           big   = (char*)alloc(41943040ull + 1310720ull);       // qkvb(24MB) -> Pp(40MB)+Lp(1.25MB)
    float2*         tbl   = (float2*)alloc(2048ull * 32 * 8);
    unsigned short* qb    = (unsigned short*)alloc(8192ull * 1024 * 2);
    unsigned short* kb    = (unsigned short*)alloc(4ull * 4 * 2048 * 64 * 2);
    unsigned short* vt    = (unsigned short*)alloc(4ull * 4 * 64 * 2048 * 2);

    unsigned short* qkvb  = (unsigned short*)big;        // bf16 [8192][1536], dead after vtrans
    unsigned short* Pp    = (unsigned short*)big;        // bf16 partials [64][40][128][64]
    float*          Lp    = (float*)(big + 41943040ull); // fp32 [64][40][128]
    unsigned short* ybf   = xb;

    // 1) fused converts + trig
    cvt_fused<<<11008, 256, 0, stream>>>((const float4*)x, (const float4*)wq, (const float4*)wk,
                                         (const float4*)wv, (const float4*)wo,
                                         (ushort4*)xb, (ushort4*)wqkvb, (ushort4*)wob, tbl);

    // 2) QKV GEMM -> bf16 [8192x1536]
    gemm_bt_t<unsigned short><<<dim3(64, 12), 256, 0, stream>>>(xb, wqkvb, qkvb, 8192, 1536, 1024);

    // 3) RoPE + QK-norm (q,k only)
    rope_norm<<<(8192 * 20) / 4, 256, 0, stream>>>(qkvb, tbl, qb, kb);

    // 4) V transpose from qkv v-region
    vtrans<<<dim3(32, 16), 256, 0, stream>>>(qkvb, vt);

    // 5) attention partials (plain stores; every slot fully overwritten)
    attn_fwd<<<2560, 256, 0, stream>>>(qb, kb, vt, Pp, Lp);

    // 6) finalize (sum chunks, divide)
    attn_fin<<<8192, 256, 0, stream>>>(Pp, Lp, ybf);

    // 7) output GEMM -> fp32 d_out
    gemm_bt_t<float><<<dim3(64, 8), 256, 0, stream>>>(ybf, wob, out, 8192, 1024, 1024);
}

// Round 12
// 174.103 us; speedup vs baseline: 1.2832x; 1.0042x over previous
//
#include <hip/hip_runtime.h>
#include <hip/hip_bf16.h>
#include <type_traits>

typedef __attribute__((ext_vector_type(8))) __bf16 bf16x8;
typedef __attribute__((ext_vector_type(2))) float f32x2;
typedef __attribute__((ext_vector_type(4))) float f32x4;
typedef __attribute__((ext_vector_type(16))) float f32x16;

#define MFMA16(a, b, c) __builtin_amdgcn_mfma_f32_16x16x32_bf16((a), (b), (c), 0, 0, 0)
#define MFMA32(a, b, c) __builtin_amdgcn_mfma_f32_32x32x16_bf16((a), (b), (c), 0, 0, 0)

__device__ __forceinline__ unsigned short f2bf(float f) {
    unsigned u = __builtin_bit_cast(unsigned, f);
    u = (u + 0x7fffu + ((u >> 16) & 1u)) >> 16;
    return (unsigned short)u;
}

__device__ __forceinline__ float bf2f(unsigned short u) {
    return __builtin_bit_cast(float, (unsigned)u << 16);
}

__device__ __forceinline__ unsigned cvt_pk_bf16(float lo, float hi) {
    unsigned r;
    asm("v_cvt_pk_bf16_f32 %0, %1, %2" : "=v"(r) : "v"(lo), "v"(hi));
    return r;
}

// swaps a.hi32lanes <-> b.lo32lanes
__device__ __forceinline__ void permswap(unsigned& a, unsigned& b) {
    asm("v_permlane32_swap_b32 %0, %1" : "+v"(a), "+v"(b));
}

__device__ __forceinline__ void gll16(const void* g, void* l) {
    __builtin_amdgcn_global_load_lds((const __attribute__((address_space(1))) void*)g,
                                     (__attribute__((address_space(3))) void*)l, 16, 0, 0);
}

// ---------------- fused fp32->bf16 converts + trig table (one launch) ----------------
__global__ __launch_bounds__(256) void cvt_fused(const float4* __restrict__ x,
                                                 const float4* __restrict__ wq,
                                                 const float4* __restrict__ wk,
                                                 const float4* __restrict__ wv,
                                                 const float4* __restrict__ wo,
                                                 ushort4* __restrict__ xb,
                                                 ushort4* __restrict__ wqkvb,
                                                 ushort4* __restrict__ wob,
                                                 float2* __restrict__ tbl) {
    int i = blockIdx.x * 256 + threadIdx.x;
    if (i < 2752512) {
        const float4* src; ushort4* dst; int j;
        if (i < 2097152)      { src = x;  dst = xb;             j = i; }
        else if (i < 2359296) { src = wq; dst = wqkvb;          j = i - 2097152; }
        else if (i < 2424832) { src = wk; dst = wqkvb + 262144; j = i - 2359296; }
        else if (i < 2490368) { src = wv; dst = wqkvb + 327680; j = i - 2424832; }
        else                  { src = wo; dst = wob;            j = i - 2490368; }
        float4 v = src[j];
        ushort4 o;
        o.x = f2bf(v.x); o.y = f2bf(v.y); o.z = f2bf(v.z); o.w = f2bf(v.w);
        dst[j] = o;
    } else {
        int j = i - 2752512;              // 65536 = 2048*32
        int t = j >> 5, k = j & 31;
        float inv = powf(10000.0f, -(float)(2 * k) * (1.0f / 64.0f));
        float a = (float)t * inv;
        tbl[j] = make_float2(cosf(a), sinf(a));
    }
}

// ---------------- QKV GEMM with fused RoPE + QK-RMSNorm + V-transpose epilogue ----------------
// C = xb[8192x1024] @ wqkvb[1536x1024]^T. Each wave's 64x64 quadrant = one head (head-
// aligned N-tiles): RMS sum = local sum over j + 4-level 16-lane shfl reduce; RoPE partner
// = shfl_xor(acc,1). q (y<8): rope+norm, scale 0.125*log2e -> qb[B,H,T,D]. k (y=8,9):
// rope+norm -> kb[B,KVH,T,D]. v (y=10,11): plain bf16, stored TRANSPOSED -> vt[B,KVH,D,T].
__global__ __launch_bounds__(256) void gemm_qkv(const unsigned short* __restrict__ A,
                                                const unsigned short* __restrict__ Bt,
                                                const float2* __restrict__ tbl,
                                                unsigned short* __restrict__ qb,
                                                unsigned short* __restrict__ kb,
                                                unsigned short* __restrict__ vt) {
    const int K = 1024;
    __shared__ unsigned short As[2][128 * 32];
    __shared__ unsigned short Bs[2][128 * 32];
    const int tid = threadIdx.x;
    const int wid = tid >> 6, lane = tid & 63;
    const size_t brow = (size_t)blockIdx.x * 128, bcol = (size_t)blockIdx.y * 128;
    const int nkt = K >> 5;

    auto stage = [&](int buf, int kt) {
#pragma unroll
        for (int j = 0; j < 2; ++j) {
            int e = (j * 256 + tid) * 8;
            int r = e >> 5, c = e & 31;
            gll16(A + (brow + r) * K + kt * 32 + c, &As[buf][e]);
        }
#pragma unroll
        for (int j = 0; j < 2; ++j) {
            int e = (j * 256 + tid) * 8;
            int r = e >> 5, c = e & 31;
            gll16(Bt + (bcol + r) * K + kt * 32 + c, &Bs[buf][e]);
        }
    };

    f32x4 acc[4][4] = {};
    const int wm = (wid >> 1) * 64, wn = (wid & 1) * 64;
    const int fr = lane & 15, fk = (lane >> 4) * 8;

    stage(0, 0);
    for (int kt = 0; kt < nkt; ++kt) {
        __syncthreads();
        if (kt + 1 < nkt) stage((kt + 1) & 1, kt + 1);
        const int buf = kt & 1;
        bf16x8 af[4], bfr[4];
#pragma unroll
        for (int i = 0; i < 4; ++i)
            af[i] = *(const bf16x8*)&As[buf][(wm + i * 16 + fr) * 32 + fk];
#pragma unroll
        for (int i = 0; i < 4; ++i)
            bfr[i] = *(const bf16x8*)&Bs[buf][(wn + i * 16 + fr) * 32 + fk];
#pragma unroll
        for (int i = 0; i < 4; ++i)
#pragma unroll
            for (int j = 0; j < 4; ++j)
                acc[i][j] = MFMA16(af[i], bfr[j], acc[i][j]);
    }

    // ---------------- fused epilogue ----------------
    const int orow = (lane >> 4) * 4, ocol = lane & 15;
    const int tokrow0 = (int)brow + wm;          // + i*16 + orow + r
    const int hcol0 = (int)bcol + wn;            // head-aligned (64)

    if (blockIdx.y < 10) {
        // q/k: RoPE (in place, fp32) + RMSNorm
        float ss[4][4];
#pragma unroll
        for (int i = 0; i < 4; ++i)
#pragma unroll
            for (int r = 0; r < 4; ++r) ss[i][r] = 0.0f;
#pragma unroll
        for (int i = 0; i < 4; ++i)
#pragma unroll
            for (int j = 0; j < 4; ++j) {
                const int m = (j * 16 + ocol) >> 1;
#pragma unroll
                for (int r = 0; r < 4; ++r) {
                    float xv = acc[i][j][r];
                    float partner = __shfl_xor(xv, 1);
                    int t = (tokrow0 + i * 16 + orow + r) & 2047;
                    float2 cs = tbl[t * 32 + m];
                    float sgn = (ocol & 1) ? cs.y : -cs.y;
                    float v = fmaf(xv, cs.x, partner * sgn);
                    acc[i][j][r] = v;
                    ss[i][r] += v * v;
                }
            }
#pragma unroll
        for (int off = 1; off < 16; off <<= 1)
#pragma unroll
            for (int i = 0; i < 4; ++i)
#pragma unroll
                for (int r = 0; r < 4; ++r) ss[i][r] += __shfl_xor(ss[i][r], off);
        const bool isq = (blockIdx.y < 8);
        const float qsc = isq ? 0.18033688f : 1.0f;   // 1/sqrt(64)*log2(e) folded into q
        const int h = hcol0 >> 6;
#pragma unroll
        for (int i = 0; i < 4; ++i)
#pragma unroll
            for (int r = 0; r < 4; ++r) {
                float sc = rsqrtf(ss[i][r] * (1.0f / 64.0f) + 1e-6f) * qsc;
                int grow = tokrow0 + i * 16 + orow + r;
                int b = grow >> 11, t = grow & 2047;
                unsigned short* dst = isq
                    ? qb + (((size_t)(b * 16 + h)) * 2048 + t) * 64
                    : kb + (((size_t)(b * 4 + (h - 16))) * 2048 + t) * 64;
#pragma unroll
                for (int j = 0; j < 4; ++j)
                    dst[j * 16 + ocol] = f2bf(acc[i][j][r] * sc);
            }
    } else {
        // v: plain bf16, stored transposed to vt[B,KVH,D,T]
#pragma unroll
        for (int j = 0; j < 4; ++j) {
            int vcol = (hcol0 - 1280) + j * 16 + ocol;   // 0..255
            int kvh = vcol >> 6, d = vcol & 63;
#pragma unroll
            for (int i = 0; i < 4; ++i) {
                int grow = tokrow0 + i * 16 + orow;      // r=0 base; 4 consecutive tokens
                int b = grow >> 11, t = grow & 2047;
                ushort4 w;
#pragma unroll
                for (int r = 0; r < 4; ++r)
                    ((unsigned short*)&w)[r] = f2bf(acc[i][j][r]);
                *(ushort4*)&vt[((size_t)(b * 4 + kvh) * 64 + d) * 2048 + t] = w;
            }
        }
    }
}

// ---------------- GEMM: C(MxN) = A(MxK) @ Bt(NxK)^T, bf16 in, fp32/bf16 out ----------------
template <typename OT>
__global__ __launch_bounds__(256) void gemm_bt_t(const unsigned short* __restrict__ A,
                                                 const unsigned short* __restrict__ Bt,
                                                 OT* __restrict__ C, int M, int N, int K) {
    __shared__ unsigned short As[2][128 * 32];
    __shared__ unsigned short Bs[2][128 * 32];
    const int tid = threadIdx.x;
    const int wid = tid >> 6, lane = tid & 63;
    const size_t brow = (size_t)blockIdx.x * 128, bcol = (size_t)blockIdx.y * 128;
    const int nkt = K >> 5;

    auto stage = [&](int buf, int kt) {
#pragma unroll
        for (int j = 0; j < 2; ++j) {
            int e = (j * 256 + tid) * 8;
            int r = e >> 5, c = e & 31;
            gll16(A + (brow + r) * K + kt * 32 + c, &As[buf][e]);
        }
#pragma unroll
        for (int j = 0; j < 2; ++j) {
            int e = (j * 256 + tid) * 8;
            int r = e >> 5, c = e & 31;
            gll16(Bt + (bcol + r) * K + kt * 32 + c, &Bs[buf][e]);
        }
    };

    f32x4 acc[4][4] = {};
    const int wm = (wid >> 1) * 64, wn = (wid & 1) * 64;
    const int fr = lane & 15, fk = (lane >> 4) * 8;

    stage(0, 0);
    for (int kt = 0; kt < nkt; ++kt) {
        __syncthreads();
        if (kt + 1 < nkt) stage((kt + 1) & 1, kt + 1);
        const int buf = kt & 1;
        bf16x8 af[4], bfr[4];
#pragma unroll
        for (int i = 0; i < 4; ++i)
            af[i] = *(const bf16x8*)&As[buf][(wm + i * 16 + fr) * 32 + fk];
#pragma unroll
        for (int i = 0; i < 4; ++i)
            bfr[i] = *(const bf16x8*)&Bs[buf][(wn + i * 16 + fr) * 32 + fk];
#pragma unroll
        for (int i = 0; i < 4; ++i)
#pragma unroll
            for (int j = 0; j < 4; ++j)
                acc[i][j] = MFMA16(af[i], bfr[j], acc[i][j]);
    }

    const int orow = (lane >> 4) * 4, ocol = lane & 15;
#pragma unroll
    for (int i = 0; i < 4; ++i)
#pragma unroll
        for (int j = 0; j < 4; ++j)
#pragma unroll
            for (int r = 0; r < 4; ++r) {
                size_t idx = (brow + wm + i * 16 + orow + r) * N + (bcol + wn + j * 16 + ocol);
                if constexpr (std::is_same_v<OT, unsigned short>)
                    C[idx] = f2bf(acc[i][j][r]);
                else
                    C[idx] = acc[i][j][r];
            }
}

// ---------------- causal flash attention ----------------
// 32 q-rows/wave, 32x32 MFMA, in-register softmax (T12), static shift p=exp2(s+S0).
// __launch_bounds__(256,4). Sequential j-tiles (low liveness). 2-buffer LDS + __syncthreads.
// 4 ILP lr chains (R11: single 16-deep pk_add chain). Staging pointers hoisted + strided.
// Plain-store partial combine. XCD-chunked grid (2560 = 8*320).
__global__ __launch_bounds__(256, 4) void attn_fwd(const unsigned short* __restrict__ qb,
                                                   const unsigned short* __restrict__ kbuf,
                                                   const unsigned short* __restrict__ vt,
                                                   unsigned short* __restrict__ Pp,
                                                   float* __restrict__ Lp) {
    int orig = blockIdx.x;
    int wg = (orig & 7) * 320 + (orig >> 3);
    int bh = wg / 40;
    int u = 39 - (wg - bh * 40);          // heavy-first (large qt first)
    int qt, ci, nc;
    if (u < 4)       { qt = u;               ci = 0;            nc = 1; }
    else if (u < 12) { qt = 4 + ((u - 4) >> 1);  ci = (u - 4) & 1;  nc = 2; }
    else if (u < 24) { qt = 8 + (u - 12) / 3;    ci = (u - 12) % 3; nc = 3; }
    else             { qt = 12 + ((u - 24) >> 2); ci = (u - 24) & 3; nc = 4; }
    const int nkt = 2 * qt + 2;
    const int t0 = ci * nkt / nc, t1 = (ci + 1) * nkt / nc;
    const int qbase = qt * 128;

    int b = bh >> 4, h = bh & 15, kvh = h >> 2;
    int tid = threadIdx.x, wid = tid >> 6, lane = tid & 63;
    int qrow0 = qbase + wid * 32;
    const unsigned short* Q = qb + ((size_t)(b * 16 + h)) * 2048 * 64;
    const unsigned short* Kp = kbuf + ((size_t)(b * 4 + kvh)) * 2048 * 64;
    const unsigned short* Vp = vt + ((size_t)(b * 4 + kvh)) * 64 * 2048;
    const int q32 = lane & 31, hi = lane >> 5;
    const int swz = (q32 & 7) ^ ((q32 >> 3) & 3);

    __shared__ unsigned short Klds[2][4096];
    __shared__ unsigned short Vlds[2][4096];

    // hoisted staging pointers (advance by constant stride per kv-tile)
    const unsigned short *gk0, *gk1, *gv0, *gv1;
    {
        int t = tid, k = t >> 3, c = (t & 7) ^ (k & 7) ^ ((k >> 3) & 3);
        gk0 = Kp + ((size_t)(t0 * 64 + k)) * 64 + c * 8;
        t = 256 + tid; k = t >> 3; c = (t & 7) ^ (k & 7) ^ ((k >> 3) & 3);
        gk1 = Kp + ((size_t)(t0 * 64 + k)) * 64 + c * 8;
        t = tid; int d = t >> 3; c = (t & 7) ^ (d & 7) ^ ((d >> 3) & 3);
        gv0 = Vp + (size_t)d * 2048 + t0 * 64 + c * 8;
        t = 256 + tid; d = t >> 3; c = (t & 7) ^ (d & 7) ^ ((d >> 3) & 3);
        gv1 = Vp + (size_t)d * 2048 + t0 * 64 + c * 8;
    }
    auto stage = [&](int buf) {
        gll16(gk0, &Klds[buf][tid * 8]);        gk0 += 4096;   // 64 keys * 64 d
        gll16(gk1, &Klds[buf][2048 + tid * 8]); gk1 += 4096;
        gll16(gv0, &Vlds[buf][tid * 8]);        gv0 += 64;     // 64 keys along T
        gll16(gv1, &Vlds[buf][2048 + tid * 8]); gv1 += 64;
    };

    // Q fragments (B-operand): lane holds Q[qrow0+q32][kd*16 + hi*8 .. +7]
    bf16x8 qf[4];
#pragma unroll
    for (int kd = 0; kd < 4; ++kd)
        qf[kd] = *(const bf16x8*)&Q[(qrow0 + q32) * 64 + kd * 16 + hi * 8];

    f32x16 accO[2] = {};
    f32x2 lra = {0.0f, 0.0f}, lrb = {0.0f, 0.0f}, lrc = {0.0f, 0.0f}, lrd = {0.0f, 0.0f};
    f32x16 s0v;                            // accumulator init = -8*log2(e)
#pragma unroll
    for (int i = 0; i < 16; ++i) s0v[i] = -11.54156036f;

    stage(0);
    for (int kt = t0; kt < t1; ++kt) {
        __syncthreads();                   // drains stage(kt); guards buffer reuse
        if (kt + 1 < t1) stage((kt + 1 - t0) & 1);
        const int cur = (kt - t0) & 1;
        const int kb0 = kt * 64;
        if (kb0 <= qrow0 + 31) {           // wave-uniform causal skip
            const int qg = qrow0 + q32;
            const bool diag = (kb0 + 63 > qrow0);   // wave-uniform
            bf16x8 pf[4];
            // sequential j-tiles: s registers reused across j (peak liveness halved)
#pragma unroll
            for (int j = 0; j < 2; ++j) {
                f32x16 s = s0v;
                const int row = j * 32 + q32;
                __builtin_amdgcn_s_setprio(1);
#pragma unroll
                for (int kd = 0; kd < 4; ++kd) {
                    bf16x8 kf = *(const bf16x8*)&Klds[cur][row * 64 + ((2 * kd + hi) ^ swz) * 8];
                    s = MFMA32(kf, qf[kd], s);
                }
                __builtin_amdgcn_s_setprio(0);
                float p[16];
                if (diag) {
#pragma unroll
                    for (int r = 0; r < 16; ++r) {
                        float v = __builtin_exp2f(s[r]);
                        int key = kb0 + j * 32 + (r & 3) + 8 * (r >> 2) + 4 * hi;
                        if (key > qg) v = 0.0f;
                        p[r] = v;
                    }
                } else {
#pragma unroll
                    for (int r = 0; r < 16; ++r) p[r] = __builtin_exp2f(s[r]);
                }
                // 4 independent accumulation chains (ILP)
                {
                    f32x2 p0 = {p[0], p[1]},  p1 = {p[2], p[3]};
                    f32x2 p2 = {p[4], p[5]},  p3 = {p[6], p[7]};
                    asm("v_pk_add_f32 %0, %0, %1" : "+v"(lra) : "v"(p0));
                    asm("v_pk_add_f32 %0, %0, %1" : "+v"(lrb) : "v"(p1));
                    asm("v_pk_add_f32 %0, %0, %1" : "+v"(lrc) : "v"(p2));
                    asm("v_pk_add_f32 %0, %0, %1" : "+v"(lrd) : "v"(p3));
                    f32x2 p4 = {p[8], p[9]},  p5 = {p[10], p[11]};
                    f32x2 p6 = {p[12], p[13]}, p7 = {p[14], p[15]};
                    asm("v_pk_add_f32 %0, %0, %1" : "+v"(lra) : "v"(p4));
                    asm("v_pk_add_f32 %0, %0, %1" : "+v"(lrb) : "v"(p5));
                    asm("v_pk_add_f32 %0, %0, %1" : "+v"(lrc) : "v"(p6));
                    asm("v_pk_add_f32 %0, %0, %1" : "+v"(lrd) : "v"(p7));
                }
#pragma unroll
                for (int kl = 0; kl < 2; ++kl) {
                    unsigned c0 = cvt_pk_bf16(p[8 * kl + 0], p[8 * kl + 1]);
                    unsigned c1 = cvt_pk_bf16(p[8 * kl + 4], p[8 * kl + 5]);
                    unsigned c2 = cvt_pk_bf16(p[8 * kl + 2], p[8 * kl + 3]);
                    unsigned c3 = cvt_pk_bf16(p[8 * kl + 6], p[8 * kl + 7]);
                    permswap(c0, c1);      // c0 = word0, c1 = word2
                    permswap(c2, c3);      // c2 = word1, c3 = word3
                    union { bf16x8 v; unsigned u[4]; } pk;
                    pk.u[0] = c0; pk.u[1] = c2; pk.u[2] = c1; pk.u[3] = c3;
                    pf[j * 2 + kl] = pk.v;
                }
            }
            // O += P @ V : V^T rows (d) contiguous over keys in Vlds
            __builtin_amdgcn_s_setprio(1);
#pragma unroll
            for (int nd = 0; nd < 2; ++nd) {
                int row = nd * 32 + q32;
#pragma unroll
                for (int ks = 0; ks < 4; ++ks) {
                    bf16x8 vf = *(const bf16x8*)&Vlds[cur][row * 64 + ((2 * ks + hi) ^ swz) * 8];
                    accO[nd] = MFMA32(pf[ks], vf, accO[nd]);
                }
            }
            __builtin_amdgcn_s_setprio(0);
        }
    }

    // merge 4 chains, then cross-half: lane halves hold disjoint key subsets for same q
    asm("v_pk_add_f32 %0, %0, %1" : "+v"(lra) : "v"(lrc));
    asm("v_pk_add_f32 %0, %0, %1" : "+v"(lrb) : "v"(lrd));
    asm("v_pk_add_f32 %0, %0, %1" : "+v"(lra) : "v"(lrb));
    float lrun = lra[0] + lra[1];
    unsigned lu = __builtin_bit_cast(unsigned, lrun);
    unsigned la = lu, lb = lu;
    permswap(la, lb);
    float L = __builtin_bit_cast(float, la) + __builtin_bit_cast(float, lb);

    // plain bf16 partial stores (slot fully owned by this block; no atomics, no memset)
    unsigned short* Pw = Pp + (((size_t)bh * 40 + u) * 128 + wid * 32) * 64;
#pragma unroll
    for (int nd = 0; nd < 2; ++nd)
#pragma unroll
        for (int r = 0; r < 16; ++r) {
            int lrow = (r & 3) + 8 * (r >> 2) + 4 * hi;
            Pw[(size_t)lrow * 64 + nd * 32 + q32] = f2bf(accO[nd][r]);
        }
    if (lane < 32)
        Lp[((size_t)bh * 40 + u) * 128 + wid * 32 + q32] = L;
}

// ---------------- finalize: y[row] = (sum_ci O_ci) / (sum_ci L_ci) -> bf16 ----------------
__global__ __launch_bounds__(256) void attn_fin(const unsigned short* __restrict__ Pp,
                                                const float* __restrict__ Lp,
                                                unsigned short* __restrict__ y) {
    int idx = blockIdx.x * 256 + threadIdx.x;   // 2,097,152 = 64*2048*16
    int dg = idx & 15;
    int grow = idx >> 4;
    int bh = grow >> 11, t = grow & 2047;
    int b = bh >> 4, h = bh & 15;
    int qt = t >> 7;
    int bse, nc;
    if (qt < 4)       { bse = qt;                nc = 1; }
    else if (qt < 8)  { bse = 4 + 2 * (qt - 4);  nc = 2; }
    else if (qt < 12) { bse = 12 + 3 * (qt - 8); nc = 3; }
    else              { bse = 24 + 4 * (qt - 12); nc = 4; }
    float o0 = 0.f, o1 = 0.f, o2 = 0.f, o3 = 0.f, L = 0.f;
    for (int ci = 0; ci < nc; ++ci) {
        size_t slot = ((size_t)bh * 40 + bse + ci) * 128 + (t & 127);
        ushort4 pw = *(const ushort4*)&Pp[slot * 64 + dg * 4];
        o0 += bf2f(pw.x); o1 += bf2f(pw.y); o2 += bf2f(pw.z); o3 += bf2f(pw.w);
        L += Lp[slot];
    }
    float inv = 1.0f / L;
    ushort4 w;
    w.x = f2bf(o0 * inv); w.y = f2bf(o1 * inv);
    w.z = f2bf(o2 * inv); w.w = f2bf(o3 * inv);
    *(ushort4*)&y[((size_t)(b * 2048 + t)) * 1024 + h * 64 + dg * 4] = w;
}

extern "C" void kernel_launch(void* const* d_in, const int* in_sizes, int n_in,
                              void* d_out, int out_size, void* d_ws, size_t ws_size,
                              hipStream_t stream) {
    const float* x = (const float*)d_in[0];
    const float* wq = (const float*)d_in[1];
    const float* wk = (const float*)d_in[2];
    const float* wv = (const float*)d_in[3];
    const float* wo = (const float*)d_in[4];
    float* out = (float*)d_out;

    char* ws = (char*)d_ws;
    size_t off = 0;
    auto alloc = [&](size_t bytes) {
        void* p = ws + off;
        off += (bytes + 255) & ~(size_t)255;
        return p;
    };
    unsigned short* xb    = (unsigned short*)alloc(8192ull * 1024 * 2);   // dead after gemm_qkv; reused as ybf
    unsigned short* wqkvb = (unsigned short*)alloc(1536ull * 1024 * 2);
    unsigned short* wob   = (unsigned short*)alloc(1024ull * 1024 * 2);
    unsigned short* Pp    = (unsigned short*)alloc(41943040ull);          // bf16 partials [64][40][128][64]
    float*          Lp    = (float*)alloc(1310720ull);                    // fp32 [64][40][128]
    float2*         tbl   = (float2*)alloc(2048ull * 32 * 8);
    unsigned short* qb    = (unsigned short*)alloc(8192ull * 1024 * 2);
    unsigned short* kb    = (unsigned short*)alloc(4ull * 4 * 2048 * 64 * 2);
    unsigned short* vt    = (unsigned short*)alloc(4ull * 4 * 64 * 2048 * 2);
    unsigned short* ybf   = xb;

    // 1) fused converts + trig
    cvt_fused<<<11008, 256, 0, stream>>>((const float4*)x, (const float4*)wq, (const float4*)wk,
                                         (const float4*)wv, (const float4*)wo,
                                         (ushort4*)xb, (ushort4*)wqkvb, (ushort4*)wob, tbl);

    // 2) QKV GEMM with fused RoPE/RMSNorm/V-transpose epilogue
    gemm_qkv<<<dim3(64, 12), 256, 0, stream>>>(xb, wqkvb, tbl, qb, kb, vt);

    // 3) attention partials (plain stores; every slot fully overwritten)
    attn_fwd<<<2560, 256, 0, stream>>>(qb, kb, vt, Pp, Lp);

    // 4) finalize (sum chunks, divide)
    attn_fin<<<8192, 256, 0, stream>>>(Pp, Lp, ybf);

    // 5) output GEMM -> fp32 d_out
    gemm_bt_t<float><<<dim3(64, 8), 256, 0, stream>>>(ybf, wob, out, 8192, 1024, 1024);
}